// Round 17
// baseline (1963.879 us; speedup 1.0000x reference)
//
#include <hip/hip_runtime.h>
#include <hip/hip_fp16.h>

typedef _Float16 half8 __attribute__((ext_vector_type(8)));
typedef float floatx16 __attribute__((ext_vector_type(16)));

#define HID 501
#define TT  200
#define BB  256
#define VV  71
#define HP  512

// ---------------- ws layout (bytes) ----------------
#define OFF_BAR   0ull                        // 8 tiles x 32 flags (dwords)
#define OFF_HFRAG 4096ull
#define SZ_HFRAG  (2ull*8*32*512*2)           // [par][tile][kstep32][lane64][8] fp16
#define OFF_HFIN  (OFF_HFRAG + SZ_HFRAG)
#define SZ_HFIN   (256ull*512*4)              // [b][hp] f32
#define OFF_GI1   (OFF_HFIN + SZ_HFIN)
#define SZ_GI1    (256ull*1536*4)             // [b][m] f32 (x*Wih1 + bih1)
#define OFF_BIAS  (OFF_GI1 + SZ_GI1)
#define SZ_BIAS   (65536ull)                  // [3][2][1536] f32
#define OFF_WD    (OFF_BIAS + SZ_BIAS)
#define SZ_WD     (96ull*512*2)               // [96][512] fp16
#define OFF_BD    (OFF_WD + SZ_WD)
#define SZ_BD     4096ull
#define OFF_W     (OFF_BD + SZ_BD)
#define SZ_W      (3ull*2*32*2*32*1024*2)     // [L][pl][blk32][rt2][row32][k1024] fp16
#define OFF_OFRAG (OFF_W + SZ_W)
#define SZ_OBUF   (8ull*200*32*512*2)         // [tile][t][kstep32][lane64][8] fp16
#define WS_NEED   (OFF_OFRAG + 2ull*SZ_OBUF)  // ~132.8 MB

// ---- MALL-coherent (cross-XCD safe) ops: bypass L1+L2 via sc0 sc1 ----
#define COH_LD16(dst, p) \
  asm volatile("global_load_dwordx4 %0, %1, off sc0 sc1" : "=&v"(dst) : "v"(p) : "memory")
__device__ __forceinline__ void coh_store16(_Float16* p, half8 v) {
  asm volatile("global_store_dwordx4 %0, %1, off sc0 sc1" :: "v"(p), "v"(v) : "memory");
}
__device__ __forceinline__ void coh_st4(unsigned* p, unsigned v) {
  asm volatile("global_store_dword %0, %1, off sc0 sc1" :: "v"(p), "v"(v) : "memory");
}
__device__ __forceinline__ float tanh_fast(float x) {
  float e = __expf(2.f*x);
  return 1.f - 2.f/(e + 1.f);
}

// ---------------- weight prep: [L][pl][blk][rt][row][k] fp16 hi/lo ----------------
// blk = hglob>>4 (16 h-cols per slice); rt0 rows = [r hl0-15 | z hl0-15],
// rt1 rows = [n hl0-15 | 16 pad]. k<512: Wih (L>0), k>=512: Whh.
__global__ __launch_bounds__(256) void prep_weights(
    const float* __restrict__ wih1, const float* __restrict__ whh1,
    const float* __restrict__ wih2, const float* __restrict__ whh2,
    const float* __restrict__ wih3, const float* __restrict__ whh3,
    _Float16* __restrict__ wbuf)
{
  const float* WIH[3] = {wih1, wih2, wih3};
  const float* WHH[3] = {whh1, whh2, whh3};
  const long total = 3ll << 21;               // 3*32blk*2rt*32row*1024k
  for (long idx = (long)blockIdx.x*256 + threadIdx.x; idx < total; idx += (long)gridDim.x*256) {
    int k   = (int)(idx & 1023);
    int row = (int)((idx >> 10) & 31);
    int rt  = (int)((idx >> 15) & 1);
    int blk = (int)((idx >> 16) & 31);
    int L   = (int)(idx >> 21);
    int g, hl; bool ok;
    if (rt == 0) { g = row >> 4; hl = row & 15; ok = true; }
    else         { g = 2;        hl = row & 15; ok = (row < 16); }
    int hcol = blk*16 + hl;
    ok = ok && (hcol < HID);
    float w = 0.f;
    if (ok) {
      if (k < HP) { if (L > 0 && k < HID) w = WIH[L][(g*HID + hcol)*HID + k]; }
      else        { int kk = k - HP; if (kk < HID) w = WHH[L][(g*HID + hcol)*HID + kk]; }
    }
    _Float16 wh = (_Float16)w;
    _Float16 wl = (_Float16)(w - (float)wh);
    long oh = ((((long)(L*2+0)*32 + blk)*2 + rt)*32 + row)*1024 + k;
    long ol = ((((long)(L*2+1)*32 + blk)*2 + rt)*32 + row)*1024 + k;
    wbuf[oh] = wh;
    wbuf[ol] = wl;
  }
}

// ---------------- misc prep: gi1, biases, decoder weights ----------------
__global__ __launch_bounds__(256) void prep_misc(
    const float* __restrict__ x, const float* __restrict__ wih1,
    const float* __restrict__ bih1, const float* __restrict__ bhh1,
    const float* __restrict__ bih2, const float* __restrict__ bhh2,
    const float* __restrict__ bih3, const float* __restrict__ bhh3,
    const float* __restrict__ wd, const float* __restrict__ bd,
    float* __restrict__ gi1, float* __restrict__ bias,
    _Float16* __restrict__ wdbuf, float* __restrict__ bdbuf)
{
  const int N1 = 256*1536;
  const int N2 = 3*2*1536;
  const int N3 = 96*512;
  const int N4 = 96;
  for (int idx = blockIdx.x*256 + threadIdx.x; idx < N1+N2+N3+N4; idx += gridDim.x*256) {
    if (idx < N1) {
      int b = idx / 1536, m = idx % 1536;
      int g = m >> 9, hc = m & 511;
      float v = 0.f;
      if (hc < HID) { int r = g*HID + hc; v = x[b]*wih1[r] + bih1[r]; }
      gi1[idx] = v;
    } else if (idx < N1+N2) {
      int i2 = idx - N1;
      int L = i2 / (2*1536);
      int rest = i2 % (2*1536);
      int pl = rest / 1536, m = rest % 1536;
      int g = m >> 9, hc = m & 511;
      float v = 0.f;
      if (hc < HID) {
        int r = g*HID + hc;
        if (pl == 0) v = (L==0) ? 0.f : (L==1 ? bih2[r] : bih3[r]);   // L0 b_ih in gi1
        else         v = (L==0) ? bhh1[r] : (L==1 ? bhh2[r] : bhh3[r]);
      }
      bias[i2] = v;
    } else if (idx < N1+N2+N3) {
      int i3 = idx - (N1+N2);
      int v = i3 >> 9, k = i3 & 511;
      float val = (v < VV && k < HID) ? wd[v*HID + k] : 0.f;
      wdbuf[i3] = (_Float16)val;
    } else {
      int v = idx - (N1+N2+N3);
      bdbuf[v] = (v < VV) ? bd[v] : 0.f;
    }
  }
}

// ---------------- recurrent layer kernel ----------------
// 256 blocks, 512 threads, 1 block/CU. Block = 16 h-cols x 1 batch-tile
// (tile = bid&7, sl = bid>>3); group = 32 blocks per tile. SAFE sc0sc1
// protocol; LDS doorbell (R16). NEW role split:
//   wave5 = publisher+poller (h-store ack OVERLAPPED with poll flight via
//           counted vmcnt; own slice excluded from poll predicate),
//   wave6 = o-store, wave0-3 = pure x (never touch the publish chain),
//   waves 4,6,7 (+0-4,6,7 for L0) = h-compute, spin on doorbell.
template<int L>
__global__ __launch_bounds__(512, 1) void gru_layer_k(
    const _Float16* __restrict__ wbuf,
    const _Float16* __restrict__ osrc,
    _Float16* __restrict__ odst,
    _Float16* __restrict__ hfrag,
    float* __restrict__ hfin,
    const float* __restrict__ gi1,
    const float* __restrict__ bias,
    unsigned* __restrict__ flags)
{
  constexpr int KPW = (L==0) ? 4 : 8;        // ksteps (of 16) per wave
  const int bid  = blockIdx.x;               // 256 blocks
  const int tile = bid & 7;                  // barrier group (32 blocks, 1 tile)
  const int sl   = bid >> 3;                 // 0..31: h-cols sl*16..sl*16+15
  const int tid  = threadIdx.x;
  const int w    = tid >> 6;
  const int lane = tid & 63;

  __shared__ float    ldsC[8][2][32][32];    // [wave][rowtile][row32][b32]
  __shared__ _Float16 ldsH[2][32][16];       // [h|o][b][hl]
  __shared__ unsigned ldsFlag;               // doorbell: last step whose poll passed

  if (tid == 0)
    __hip_atomic_store(&ldsFlag, 0u, __ATOMIC_RELAXED, __HIP_MEMORY_SCOPE_WORKGROUP);
  // init visibility: tid0.init -> B(0) -> first reads at t=1

  // ---- persistent weight fragments: Wf[pl][rt][i] ----
  half8 Wf[2][2][KPW];
  {
    int row = lane & 31;
    int kc  = (lane >> 5) << 3;
    int ks0 = (L==0) ? (32 + w*4) : (w*8);
    #pragma unroll
    for (int pl = 0; pl < 2; ++pl)
      #pragma unroll
      for (int rt = 0; rt < 2; ++rt)
        #pragma unroll
        for (int i = 0; i < KPW; ++i) {
          long off = ((((long)(L*2+pl)*32 + sl)*2 + rt)*32 + row)*1024 + (long)(ks0+i)*16 + kc;
          Wf[pl][rt][i] = *(const half8*)(wbuf + off);
        }
  }

  // ---- gate-thread state: (b = tid&31, hl = (tid>>5)&15) covers 32x16 ----
  const int b     = tid & 31;
  const int hl    = (tid >> 5) & 15;
  const int bglob = tile*32 + b;
  const int hglob = sl*16 + hl;
  float hreg = 0.f;
  float bih[3], bhh[3], gi[3] = {0,0,0};
  if (L > 0) hreg = hfin[bglob*HP + hglob];
  #pragma unroll
  for (int g = 0; g < 3; ++g) {
    bih[g] = bias[(L*2+0)*1536 + g*512 + hglob];
    bhh[g] = bias[(L*2+1)*1536 + g*512 + hglob];
    if (L == 0) gi[g] = gi1[(long)bglob*1536 + g*512 + hglob];
  }

  const long hf_par  = 8ll*32*512;
  const long hf_tile = (long)tile*(32*512);
  const long ob_t    = (long)tile*200*(32*512);
  const long region  = (long)sl*512;         // block's contiguous 1KB frag region
  unsigned* fl = flags + tile*32;
  unsigned dead = 0;

  for (int t = 0; t < TT; ++t) {
    // ---- x-part (L>0, waves 0-3): pure compute, bounded only by B ----
    if (L > 0 && w < 4) {
      const _Float16* xb = osrc + ob_t + (long)t*(32*512) + (long)(w*8)*512 + lane*8;
      half8 X[8];
      #pragma unroll
      for (int i = 0; i < 8; ++i) X[i] = *(const half8*)(xb + i*512);
      floatx16 C0, C1;
      #pragma unroll
      for (int i = 0; i < 16; ++i) { C0[i] = 0.f; C1[i] = 0.f; }
      #pragma unroll
      for (int i = 0; i < 8; ++i) {
        C0 = __builtin_amdgcn_mfma_f32_32x32x16_f16(Wf[0][0][i], X[i], C0, 0, 0, 0);
        C0 = __builtin_amdgcn_mfma_f32_32x32x16_f16(Wf[1][0][i], X[i], C0, 0, 0, 0);
        C1 = __builtin_amdgcn_mfma_f32_32x32x16_f16(Wf[0][1][i], X[i], C1, 0, 0, 0);
        C1 = __builtin_amdgcn_mfma_f32_32x32x16_f16(Wf[1][1][i], X[i], C1, 0, 0, 0);
      }
      int col = lane & 31, rb = (lane >> 5) << 2;
      #pragma unroll
      for (int r = 0; r < 16; ++r) {
        int rowm = (r & 3) + 8*(r >> 2) + rb;
        ldsC[w][0][rowm][col] = C0[r];
        ldsC[w][1][rowm][col] = C1[r];
      }
    }
    // ---- h-part: doorbell spin (non-poll h-waves) -> MALL loads -> MFMA ----
    if ((L == 0 || w >= 4) && !(L == 0 && t == 0)) {
      if (t > 0 && w != 5) {                 // wave5 owns the poll; others spin on LDS
        unsigned tries = 0;
        while (__hip_atomic_load(&ldsFlag, __ATOMIC_ACQUIRE,
                                 __HIP_MEMORY_SCOPE_WORKGROUP) < (unsigned)t) {
          if (++tries > (1u<<18)) { dead = 1; break; }   // visible fail, no wedge
        }
        __builtin_amdgcn_sched_barrier(0);
      }
      const int hs0 = (L==0) ? (w*4) : ((w-4)*8);
      const _Float16* hp = hfrag + (long)(t & 1)*hf_par + hf_tile + (long)hs0*512 + lane*8;
      half8 H[KPW];
      #pragma unroll
      for (int i = 0; i < KPW; ++i) COH_LD16(H[i], hp + i*512);
      asm volatile("s_waitcnt vmcnt(0)" ::: "memory");
      __builtin_amdgcn_sched_barrier(0);
      floatx16 C0, C1;
      #pragma unroll
      for (int i = 0; i < 16; ++i) { C0[i] = 0.f; C1[i] = 0.f; }
      #pragma unroll
      for (int i = 0; i < KPW; ++i) {
        C0 = __builtin_amdgcn_mfma_f32_32x32x16_f16(Wf[0][0][i], H[i], C0, 0, 0, 0);
        C0 = __builtin_amdgcn_mfma_f32_32x32x16_f16(Wf[1][0][i], H[i], C0, 0, 0, 0);
        C1 = __builtin_amdgcn_mfma_f32_32x32x16_f16(Wf[0][1][i], H[i], C1, 0, 0, 0);
        C1 = __builtin_amdgcn_mfma_f32_32x32x16_f16(Wf[1][1][i], H[i], C1, 0, 0, 0);
      }
      int col = lane & 31, rb = (lane >> 5) << 2;
      #pragma unroll
      for (int r = 0; r < 16; ++r) {
        int rowm = (r & 3) + 8*(r >> 2) + rb;
        ldsC[w][0][rowm][col] = C0[r];
        ldsC[w][1][rowm][col] = C1[r];
      }
    }
    __syncthreads();                          // B: all partials complete
    // ---- gates: rt0 rows [r: hl | z: 16+hl], rt1 rows [n: hl] ----
    {
      float sx[3] = {0,0,0}, sh[3] = {0,0,0};
      if (!(L == 0 && t == 0)) {
        #pragma unroll
        for (int g = 0; g < 3; ++g) {
          int rt  = (g == 2) ? 1 : 0;
          int row = (g == 2) ? hl : g*16 + hl;
          float ax = 0.f, ah = 0.f;
          if (L == 0) {
            #pragma unroll
            for (int ww = 0; ww < 8; ++ww) ah += ldsC[ww][rt][row][b];
          } else {
            #pragma unroll
            for (int ww = 0; ww < 4; ++ww) ax += ldsC[ww][rt][row][b];
            #pragma unroll
            for (int ww = 4; ww < 8; ++ww) ah += ldsC[ww][rt][row][b];
          }
          sx[g] = ax; sh[g] = ah;
        }
      }
      float pr = sx[0] + gi[0] + bih[0] + sh[0] + bhh[0];
      float pz = sx[1] + gi[1] + bih[1] + sh[1] + bhh[1];
      float r = 1.f/(1.f + __expf(-pr));
      float z = 1.f/(1.f + __expf(-pz));
      float n = tanh_fast(sx[2] + gi[2] + bih[2] + r*(sh[2] + bhh[2]));
      float hn = (1.f - z)*n + z*hreg;
      hreg = hn;
      ldsH[0][b][hl] = (_Float16)hn;
      ldsH[1][b][hl] = (_Float16)tanh_fast(hn);
      if (t == TT-1) hfin[bglob*HP + hglob] = hn;
    }
    __syncthreads();                          // C: ldsH complete
    // ---- wave6: o-store (independent of the publish chain) ----
    if (w == 6) {
      int h0 = (lane >> 5) * 8;
      half8 ov = *(const half8*)&ldsH[1][lane & 31][h0];
      *(half8*)(odst + ob_t + (long)t*(32*512) + region + lane*8) = ov;
    }
    // ---- wave5: publish + (ack ∥ poll) + flag + doorbell ----
    if (w == 5) {
      int h0 = (lane >> 5) * 8;
      half8 hv = *(const half8*)&ldsH[0][lane & 31][h0];
      coh_store16(hfrag + (long)((t+1) & 1)*hf_par + hf_tile + region + lane*8, hv);
      if (t < TT-1) {
        const unsigned tgt = (unsigned)(L*(TT-1) + t + 1);
        const unsigned* fp = fl + (lane & 31);
        const bool own = ((lane & 31) == sl);
        bool okp = false;
        if (!dead) {
          unsigned v0, v1, v2, v3;
          // round 0: poll flight overlaps the h-store ack
          asm volatile(
            "global_load_dword %0, %4, off sc0 sc1\n\t"
            "global_load_dword %1, %4, off sc0 sc1\n\t"
            "global_load_dword %2, %4, off sc0 sc1\n\t"
            "global_load_dword %3, %4, off sc0 sc1"
            : "=&v"(v0), "=&v"(v1), "=&v"(v2), "=&v"(v3)
            : "v"(fp) : "memory");
          asm volatile("s_waitcnt vmcnt(4)" ::: "memory");   // h-store acked
          __builtin_amdgcn_sched_barrier(0);
          if (lane == 0) coh_st4(fl + sl, tgt);              // own flag out
          asm volatile("s_waitcnt vmcnt(4)" ::: "memory");   // v0 ready
          __builtin_amdgcn_sched_barrier(0);
          okp = __all(own || v0 >= tgt);
          if (!okp) {
            asm volatile("s_waitcnt vmcnt(3)" ::: "memory");
            __builtin_amdgcn_sched_barrier(0);
            okp = __all(own || v1 >= tgt);
          }
          if (!okp) {
            asm volatile("s_waitcnt vmcnt(2)" ::: "memory");
            __builtin_amdgcn_sched_barrier(0);
            okp = __all(own || v2 >= tgt);
          }
          if (!okp) {
            asm volatile("s_waitcnt vmcnt(1)" ::: "memory");
            __builtin_amdgcn_sched_barrier(0);
            okp = __all(own || v3 >= tgt);
          }
          unsigned tries = 0;
          while (!okp) {
            asm volatile(
              "global_load_dword %0, %4, off sc0 sc1\n\t"
              "global_load_dword %1, %4, off sc0 sc1\n\t"
              "global_load_dword %2, %4, off sc0 sc1\n\t"
              "global_load_dword %3, %4, off sc0 sc1"
              : "=&v"(v0), "=&v"(v1), "=&v"(v2), "=&v"(v3)
              : "v"(fp) : "memory");
            asm volatile("s_waitcnt vmcnt(3)" ::: "memory");
            __builtin_amdgcn_sched_barrier(0);
            if (__all(own || v0 >= tgt)) { okp = true; break; }
            asm volatile("s_waitcnt vmcnt(2)" ::: "memory");
            __builtin_amdgcn_sched_barrier(0);
            if (__all(own || v1 >= tgt)) { okp = true; break; }
            asm volatile("s_waitcnt vmcnt(1)" ::: "memory");
            __builtin_amdgcn_sched_barrier(0);
            if (__all(own || v2 >= tgt)) { okp = true; break; }
            asm volatile("s_waitcnt vmcnt(0)" ::: "memory");
            __builtin_amdgcn_sched_barrier(0);
            if (__all(own || v3 >= tgt)) { okp = true; break; }
            if (++tries > (1u<<17)) { dead = 1; break; }   // visible fail, no wedge
          }
          asm volatile("s_waitcnt vmcnt(0)" ::: "memory");   // drain stragglers
        }
        if (lane == 0)                        // post doorbell even if valve tripped
          __hip_atomic_store(&ldsFlag, (unsigned)(t + 1), __ATOMIC_RELEASE,
                             __HIP_MEMORY_SCOPE_WORKGROUP);
      }
    }
  }
}

// ---------------- decoder: relu(tanh(o3) @ Wd^T + bd) ----------------
__global__ __launch_bounds__(256, 2) void decoder_k(
    const _Float16* __restrict__ o3,
    const _Float16* __restrict__ wdbuf,
    const float* __restrict__ bdbuf,
    float* __restrict__ out)
{
  const int bx = blockIdx.x;          // 8 tiles * 25 chunks
  const int tile = bx & 7;
  const int chunk = bx >> 3;
  const int tid = threadIdx.x;
  const int w = tid >> 6, lane = tid & 63;
  __shared__ float ldsD[4][96][32];
  __shared__ float ldsO[32][73];      // 73: conflict-free write stride

  half8 Wf[3][8];
  {
    int kc = (lane >> 5) << 3;
    #pragma unroll
    for (int mt = 0; mt < 3; ++mt)
      #pragma unroll
      for (int i = 0; i < 8; ++i) {
        int row = mt*32 + (lane & 31);
        int k = (w*8 + i)*16 + kc;
        Wf[mt][i] = *(const half8*)(wdbuf + (long)row*512 + k);
      }
  }
  for (int tt = 0; tt < 8; ++tt) {
    int t = chunk*8 + tt;
    long ob = ((long)tile*200 + t)*(32*512);
    half8 Xf[8];
    #pragma unroll
    for (int i = 0; i < 8; ++i) {
      int s = w*8 + i;
      Xf[i] = *(const half8*)(o3 + ob + (long)s*512 + lane*8);
    }
    floatx16 C0, C1, C2;
    #pragma unroll
    for (int i = 0; i < 16; ++i) { C0[i] = 0.f; C1[i] = 0.f; C2[i] = 0.f; }
    #pragma unroll
    for (int i = 0; i < 8; ++i) {
      C0 = __builtin_amdgcn_mfma_f32_32x32x16_f16(Wf[0][i], Xf[i], C0, 0, 0, 0);
      C1 = __builtin_amdgcn_mfma_f32_32x32x16_f16(Wf[1][i], Xf[i], C1, 0, 0, 0);
      C2 = __builtin_amdgcn_mfma_f32_32x32x16_f16(Wf[2][i], Xf[i], C2, 0, 0, 0);
    }
    {
      int col = lane & 31;
      int rb = (lane >> 5) << 2;
      #pragma unroll
      for (int r = 0; r < 16; ++r) {
        int rowm = (r & 3) + 8*(r >> 2) + rb;
        ldsD[w][rowm][col]      = C0[r];
        ldsD[w][32 + rowm][col] = C1[r];
        ldsD[w][64 + rowm][col] = C2[r];
      }
    }
    __syncthreads();
    for (int ii = tid; ii < VV*32; ii += 256) {          // b-major: stride-1 LDS reads
      int bb = ii & 31, v = ii >> 5;
      float s = ldsD[0][v][bb] + ldsD[1][v][bb] + ldsD[2][v][bb] + ldsD[3][v][bb] + bdbuf[v];
      ldsO[bb][v] = s > 0.f ? s : 0.f;
    }
    __syncthreads();
    for (int ii = tid; ii < VV*32; ii += 256) {          // coalesced global writes
      int bb = ii / VV, v = ii - bb*VV;
      out[((long)(tile*32 + bb)*200 + t)*VV + v] = ldsO[bb][v];
    }
    __syncthreads();
  }
}

// ---------------- host ----------------
extern "C" void kernel_launch(void* const* d_in, const int* in_sizes, int n_in,
                              void* d_out, int out_size, void* d_ws, size_t ws_size,
                              hipStream_t stream) {
  (void)in_sizes; (void)n_in;
  const float* x    = (const float*)d_in[0];
  const float* wih1 = (const float*)d_in[1];
  const float* whh1 = (const float*)d_in[2];
  const float* bih1 = (const float*)d_in[3];
  const float* bhh1 = (const float*)d_in[4];
  const float* wih2 = (const float*)d_in[5];
  const float* whh2 = (const float*)d_in[6];
  const float* bih2 = (const float*)d_in[7];
  const float* bhh2 = (const float*)d_in[8];
  const float* wih3 = (const float*)d_in[9];
  const float* whh3 = (const float*)d_in[10];
  const float* bih3 = (const float*)d_in[11];
  const float* bhh3 = (const float*)d_in[12];
  const float* wd   = (const float*)d_in[13];
  const float* bd   = (const float*)d_in[14];
  char* ws = (char*)d_ws;

  if (ws_size < WS_NEED) {   // clean, visible failure rather than corruption
    hipMemsetAsync(d_out, 0, (size_t)out_size*sizeof(float), stream);
    return;
  }

  _Float16* wbuf   = (_Float16*)(ws + OFF_W);
  float*    gi1p   = (float*)(ws + OFF_GI1);
  float*    biasp  = (float*)(ws + OFF_BIAS);
  _Float16* wdbufp = (_Float16*)(ws + OFF_WD);
  float*    bdbufp = (float*)(ws + OFF_BD);
  _Float16* hfragp = (_Float16*)(ws + OFF_HFRAG);
  float*    hfinp  = (float*)(ws + OFF_HFIN);
  unsigned* flagsp = (unsigned*)(ws + OFF_BAR);
  _Float16* ob0    = (_Float16*)(ws + OFF_OFRAG);
  _Float16* ob1    = ob0 + SZ_OBUF/2;

  // zero flags each launch (memory-side MALL => visible to sc0sc1 readers)
  hipMemsetAsync(ws + OFF_BAR, 0, 4096, stream);

  prep_weights<<<4096, 256, 0, stream>>>(wih1, whh1, wih2, whh2, wih3, whh3, wbuf);
  prep_misc<<<1024, 256, 0, stream>>>(x, wih1, bih1, bhh1, bih2, bhh2, bih3, bhh3,
                                      wd, bd, gi1p, biasp, wdbufp, bdbufp);

  gru_layer_k<0><<<256, 512, 0, stream>>>(wbuf, ob1, ob0, hfragp, hfinp, gi1p, biasp, flagsp);
  gru_layer_k<1><<<256, 512, 0, stream>>>(wbuf, ob0, ob1, hfragp, hfinp, gi1p, biasp, flagsp);
  gru_layer_k<2><<<256, 512, 0, stream>>>(wbuf, ob1, ob0, hfragp, hfinp, gi1p, biasp, flagsp);

  decoder_k<<<200, 256, 0, stream>>>(ob0, wdbufp, bdbufp, (float*)d_out);
}

// Round 18
// 1900.894 us; speedup vs baseline: 1.0331x; 1.0331x over previous
//
#include <hip/hip_runtime.h>
#include <hip/hip_fp16.h>

typedef _Float16 half8 __attribute__((ext_vector_type(8)));
typedef float floatx16 __attribute__((ext_vector_type(16)));

#define HID 501
#define TT  200
#define BB  256
#define VV  71
#define HP  512

// ---------------- ws layout (bytes) ----------------
#define OFF_BAR   0ull                        // 8 tiles x 32 flags (dwords)
#define OFF_HFRAG 4096ull
#define SZ_HFRAG  (2ull*8*32*512*2)           // [par][tile][kstep32][lane64][8] fp16
#define OFF_HFIN  (OFF_HFRAG + SZ_HFRAG)
#define SZ_HFIN   (256ull*512*4)              // [b][hp] f32
#define OFF_GI1   (OFF_HFIN + SZ_HFIN)
#define SZ_GI1    (256ull*1536*4)             // [b][m] f32 (x*Wih1 + bih1)
#define OFF_BIAS  (OFF_GI1 + SZ_GI1)
#define SZ_BIAS   (65536ull)                  // [3][2][1536] f32
#define OFF_WD    (OFF_BIAS + SZ_BIAS)
#define SZ_WD     (96ull*512*2)               // [96][512] fp16
#define OFF_BD    (OFF_WD + SZ_WD)
#define SZ_BD     4096ull
#define OFF_W     (OFF_BD + SZ_BD)
#define SZ_W      (3ull*2*32*2*32*1024*2)     // [L][pl][blk32][rt2][row32][k1024] fp16
#define OFF_OFRAG (OFF_W + SZ_W)
#define SZ_OBUF   (8ull*200*32*512*2)         // [tile][t][kstep32][lane64][8] fp16
#define WS_NEED   (OFF_OFRAG + 2ull*SZ_OBUF)  // ~132.8 MB

// ---- MALL-coherent (cross-XCD safe) ops: bypass L1+L2 via sc0 sc1 ----
#define COH_LD16(dst, p) \
  asm volatile("global_load_dwordx4 %0, %1, off sc0 sc1" : "=&v"(dst) : "v"(p) : "memory")
__device__ __forceinline__ void coh_store16(_Float16* p, half8 v) {
  asm volatile("global_store_dwordx4 %0, %1, off sc0 sc1" :: "v"(p), "v"(v) : "memory");
}
__device__ __forceinline__ void coh_st4(unsigned* p, unsigned v) {
  asm volatile("global_store_dword %0, %1, off sc0 sc1" :: "v"(p), "v"(v) : "memory");
}
__device__ __forceinline__ float tanh_fast(float x) {
  float e = __expf(2.f*x);
  return 1.f - 2.f/(e + 1.f);
}

// ---------------- weight prep: [L][pl][blk][rt][row][k] fp16 hi/lo ----------------
// blk = hglob>>4 (16 h-cols per slice); rt0 rows = [r hl0-15 | z hl0-15],
// rt1 rows = [n hl0-15 | 16 pad]. k<512: Wih (L>0), k>=512: Whh.
__global__ __launch_bounds__(256) void prep_weights(
    const float* __restrict__ wih1, const float* __restrict__ whh1,
    const float* __restrict__ wih2, const float* __restrict__ whh2,
    const float* __restrict__ wih3, const float* __restrict__ whh3,
    _Float16* __restrict__ wbuf)
{
  const float* WIH[3] = {wih1, wih2, wih3};
  const float* WHH[3] = {whh1, whh2, whh3};
  const long total = 3ll << 21;               // 3*32blk*2rt*32row*1024k
  for (long idx = (long)blockIdx.x*256 + threadIdx.x; idx < total; idx += (long)gridDim.x*256) {
    int k   = (int)(idx & 1023);
    int row = (int)((idx >> 10) & 31);
    int rt  = (int)((idx >> 15) & 1);
    int blk = (int)((idx >> 16) & 31);
    int L   = (int)(idx >> 21);
    int g, hl; bool ok;
    if (rt == 0) { g = row >> 4; hl = row & 15; ok = true; }
    else         { g = 2;        hl = row & 15; ok = (row < 16); }
    int hcol = blk*16 + hl;
    ok = ok && (hcol < HID);
    float w = 0.f;
    if (ok) {
      if (k < HP) { if (L > 0 && k < HID) w = WIH[L][(g*HID + hcol)*HID + k]; }
      else        { int kk = k - HP; if (kk < HID) w = WHH[L][(g*HID + hcol)*HID + kk]; }
    }
    _Float16 wh = (_Float16)w;
    _Float16 wl = (_Float16)(w - (float)wh);
    long oh = ((((long)(L*2+0)*32 + blk)*2 + rt)*32 + row)*1024 + k;
    long ol = ((((long)(L*2+1)*32 + blk)*2 + rt)*32 + row)*1024 + k;
    wbuf[oh] = wh;
    wbuf[ol] = wl;
  }
}

// ---------------- misc prep: gi1, biases, decoder weights ----------------
__global__ __launch_bounds__(256) void prep_misc(
    const float* __restrict__ x, const float* __restrict__ wih1,
    const float* __restrict__ bih1, const float* __restrict__ bhh1,
    const float* __restrict__ bih2, const float* __restrict__ bhh2,
    const float* __restrict__ bih3, const float* __restrict__ bhh3,
    const float* __restrict__ wd, const float* __restrict__ bd,
    float* __restrict__ gi1, float* __restrict__ bias,
    _Float16* __restrict__ wdbuf, float* __restrict__ bdbuf)
{
  const int N1 = 256*1536;
  const int N2 = 3*2*1536;
  const int N3 = 96*512;
  const int N4 = 96;
  for (int idx = blockIdx.x*256 + threadIdx.x; idx < N1+N2+N3+N4; idx += gridDim.x*256) {
    if (idx < N1) {
      int b = idx / 1536, m = idx % 1536;
      int g = m >> 9, hc = m & 511;
      float v = 0.f;
      if (hc < HID) { int r = g*HID + hc; v = x[b]*wih1[r] + bih1[r]; }
      gi1[idx] = v;
    } else if (idx < N1+N2) {
      int i2 = idx - N1;
      int L = i2 / (2*1536);
      int rest = i2 % (2*1536);
      int pl = rest / 1536, m = rest % 1536;
      int g = m >> 9, hc = m & 511;
      float v = 0.f;
      if (hc < HID) {
        int r = g*HID + hc;
        if (pl == 0) v = (L==0) ? 0.f : (L==1 ? bih2[r] : bih3[r]);   // L0 b_ih in gi1
        else         v = (L==0) ? bhh1[r] : (L==1 ? bhh2[r] : bhh3[r]);
      }
      bias[i2] = v;
    } else if (idx < N1+N2+N3) {
      int i3 = idx - (N1+N2);
      int v = i3 >> 9, k = i3 & 511;
      float val = (v < VV && k < HID) ? wd[v*HID + k] : 0.f;
      wdbuf[i3] = (_Float16)val;
    } else {
      int v = idx - (N1+N2+N3);
      bdbuf[v] = (v < VV) ? bd[v] : 0.f;
    }
  }
}

// ---------------- recurrent layer kernel ----------------
// 256 blocks, 512 threads, 1 block/CU. Block = 16 h-cols x 1 batch-tile
// (tile = bid&7, sl = bid>>3); group = 32 blocks per tile. SAFE sc0sc1
// protocol; wave5 end-of-iter MALL poll -> LDS doorbell (R16 best config:
// publish on wave0 CONCURRENT with wave5's poll; x-waves 0-3 never wait
// for the poll — their only sync is barrier B).
template<int L>
__global__ __launch_bounds__(512, 1) void gru_layer_k(
    const _Float16* __restrict__ wbuf,
    const _Float16* __restrict__ osrc,
    _Float16* __restrict__ odst,
    _Float16* __restrict__ hfrag,
    float* __restrict__ hfin,
    const float* __restrict__ gi1,
    const float* __restrict__ bias,
    unsigned* __restrict__ flags)
{
  constexpr int KPW = (L==0) ? 4 : 8;        // ksteps (of 16) per wave
  const int bid  = blockIdx.x;               // 256 blocks
  const int tile = bid & 7;                  // barrier group (32 blocks, 1 tile)
  const int sl   = bid >> 3;                 // 0..31: h-cols sl*16..sl*16+15
  const int tid  = threadIdx.x;
  const int w    = tid >> 6;
  const int lane = tid & 63;

  __shared__ float    ldsC[8][2][32][32];    // [wave][rowtile][row32][b32]
  __shared__ _Float16 ldsH[2][32][16];       // [h|o][b][hl]
  __shared__ unsigned ldsFlag;               // doorbell: last step whose poll passed

  if (tid == 0)
    __hip_atomic_store(&ldsFlag, 0u, __ATOMIC_RELAXED, __HIP_MEMORY_SCOPE_WORKGROUP);
  // visibility of init: tid0.init -> B(0) -> everyone's first read (t=1)

  // ---- persistent weight fragments: Wf[pl][rt][i] ----
  half8 Wf[2][2][KPW];
  {
    int row = lane & 31;
    int kc  = (lane >> 5) << 3;
    int ks0 = (L==0) ? (32 + w*4) : (w*8);
    #pragma unroll
    for (int pl = 0; pl < 2; ++pl)
      #pragma unroll
      for (int rt = 0; rt < 2; ++rt)
        #pragma unroll
        for (int i = 0; i < KPW; ++i) {
          long off = ((((long)(L*2+pl)*32 + sl)*2 + rt)*32 + row)*1024 + (long)(ks0+i)*16 + kc;
          Wf[pl][rt][i] = *(const half8*)(wbuf + off);
        }
  }

  // ---- gate-thread state: (b = tid&31, hl = (tid>>5)&15) covers 32x16 ----
  const int b     = tid & 31;
  const int hl    = (tid >> 5) & 15;
  const int bglob = tile*32 + b;
  const int hglob = sl*16 + hl;
  float hreg = 0.f;
  float bih[3], bhh[3], gi[3] = {0,0,0};
  if (L > 0) hreg = hfin[bglob*HP + hglob];
  #pragma unroll
  for (int g = 0; g < 3; ++g) {
    bih[g] = bias[(L*2+0)*1536 + g*512 + hglob];
    bhh[g] = bias[(L*2+1)*1536 + g*512 + hglob];
    if (L == 0) gi[g] = gi1[(long)bglob*1536 + g*512 + hglob];
  }

  const long hf_par  = 8ll*32*512;
  const long hf_tile = (long)tile*(32*512);
  const long ob_t    = (long)tile*200*(32*512);
  const long region  = (long)sl*512;         // block's contiguous 1KB frag region
  unsigned* fl = flags + tile*32;
  unsigned dead = 0;

  for (int t = 0; t < TT; ++t) {
    // ---- x-part (L>0, waves 0-3): no poll dependency, bounded only by B ----
    if (L > 0 && w < 4) {
      const _Float16* xb = osrc + ob_t + (long)t*(32*512) + (long)(w*8)*512 + lane*8;
      half8 X[8];
      #pragma unroll
      for (int i = 0; i < 8; ++i) X[i] = *(const half8*)(xb + i*512);
      floatx16 C0, C1;
      #pragma unroll
      for (int i = 0; i < 16; ++i) { C0[i] = 0.f; C1[i] = 0.f; }
      #pragma unroll
      for (int i = 0; i < 8; ++i) {
        C0 = __builtin_amdgcn_mfma_f32_32x32x16_f16(Wf[0][0][i], X[i], C0, 0, 0, 0);
        C0 = __builtin_amdgcn_mfma_f32_32x32x16_f16(Wf[1][0][i], X[i], C0, 0, 0, 0);
        C1 = __builtin_amdgcn_mfma_f32_32x32x16_f16(Wf[0][1][i], X[i], C1, 0, 0, 0);
        C1 = __builtin_amdgcn_mfma_f32_32x32x16_f16(Wf[1][1][i], X[i], C1, 0, 0, 0);
      }
      int col = lane & 31, rb = (lane >> 5) << 2;
      #pragma unroll
      for (int r = 0; r < 16; ++r) {
        int rowm = (r & 3) + 8*(r >> 2) + rb;
        ldsC[w][0][rowm][col] = C0[r];
        ldsC[w][1][rowm][col] = C1[r];
      }
    }
    // ---- h-part: doorbell spin (non-poll h-waves) -> MALL loads -> MFMA ----
    if ((L == 0 || w >= 4) && !(L == 0 && t == 0)) {
      if (t > 0 && w != 5) {                 // wave5 owns the poll; others spin on LDS
        unsigned tries = 0;
        while (__hip_atomic_load(&ldsFlag, __ATOMIC_ACQUIRE,
                                 __HIP_MEMORY_SCOPE_WORKGROUP) < (unsigned)t) {
          if (++tries > (1u<<18)) { dead = 1; break; }   // visible fail, no wedge
        }
        __builtin_amdgcn_sched_barrier(0);
      }
      const int hs0 = (L==0) ? (w*4) : ((w-4)*8);
      const _Float16* hp = hfrag + (long)(t & 1)*hf_par + hf_tile + (long)hs0*512 + lane*8;
      half8 H[KPW];
      #pragma unroll
      for (int i = 0; i < KPW; ++i) COH_LD16(H[i], hp + i*512);
      asm volatile("s_waitcnt vmcnt(0)" ::: "memory");
      __builtin_amdgcn_sched_barrier(0);
      floatx16 C0, C1;
      #pragma unroll
      for (int i = 0; i < 16; ++i) { C0[i] = 0.f; C1[i] = 0.f; }
      #pragma unroll
      for (int i = 0; i < KPW; ++i) {
        C0 = __builtin_amdgcn_mfma_f32_32x32x16_f16(Wf[0][0][i], H[i], C0, 0, 0, 0);
        C0 = __builtin_amdgcn_mfma_f32_32x32x16_f16(Wf[1][0][i], H[i], C0, 0, 0, 0);
        C1 = __builtin_amdgcn_mfma_f32_32x32x16_f16(Wf[0][1][i], H[i], C1, 0, 0, 0);
        C1 = __builtin_amdgcn_mfma_f32_32x32x16_f16(Wf[1][1][i], H[i], C1, 0, 0, 0);
      }
      int col = lane & 31, rb = (lane >> 5) << 2;
      #pragma unroll
      for (int r = 0; r < 16; ++r) {
        int rowm = (r & 3) + 8*(r >> 2) + rb;
        ldsC[w][0][rowm][col] = C0[r];
        ldsC[w][1][rowm][col] = C1[r];
      }
    }
    __syncthreads();                          // B: all partials complete
    // ---- gates: rt0 rows [r: hl | z: 16+hl], rt1 rows [n: hl] ----
    {
      float sx[3] = {0,0,0}, sh[3] = {0,0,0};
      if (!(L == 0 && t == 0)) {
        #pragma unroll
        for (int g = 0; g < 3; ++g) {
          int rt  = (g == 2) ? 1 : 0;
          int row = (g == 2) ? hl : g*16 + hl;
          float ax = 0.f, ah = 0.f;
          if (L == 0) {
            #pragma unroll
            for (int ww = 0; ww < 8; ++ww) ah += ldsC[ww][rt][row][b];
          } else {
            #pragma unroll
            for (int ww = 0; ww < 4; ++ww) ax += ldsC[ww][rt][row][b];
            #pragma unroll
            for (int ww = 4; ww < 8; ++ww) ah += ldsC[ww][rt][row][b];
          }
          sx[g] = ax; sh[g] = ah;
        }
      }
      float pr = sx[0] + gi[0] + bih[0] + sh[0] + bhh[0];
      float pz = sx[1] + gi[1] + bih[1] + sh[1] + bhh[1];
      float r = 1.f/(1.f + __expf(-pr));
      float z = 1.f/(1.f + __expf(-pz));
      float n = tanh_fast(sx[2] + gi[2] + bih[2] + r*(sh[2] + bhh[2]));
      float hn = (1.f - z)*n + z*hreg;
      hreg = hn;
      ldsH[0][b][hl] = (_Float16)hn;
      ldsH[1][b][hl] = (_Float16)tanh_fast(hn);
      if (t == TT-1) hfin[bglob*HP + hglob] = hn;
    }
    __syncthreads();                          // C: ldsH complete
    // ---- publish (wave0): h-stores -> vmcnt(0) -> flag; o-store after ----
    if (tid < 64) {
      int h0 = (tid >> 5) * 8;
      half8 hv = *(const half8*)&ldsH[0][tid & 31][h0];
      coh_store16(hfrag + (long)((t+1) & 1)*hf_par + hf_tile + region + tid*8, hv);
    }
    if (w == 0) {
      asm volatile("s_waitcnt vmcnt(0)" ::: "memory");   // h at MALL before flag
      if (tid == 0 && t < TT-1)
        coh_st4(fl + sl, (unsigned)(L*(TT-1) + t + 1));
    }
    if (tid < 64) {   // o-store off the critical chain (after flag)
      int h0 = (tid >> 5) * 8;
      half8 ov = *(const half8*)&ldsH[1][tid & 31][h0];
      *(half8*)(odst + ob_t + (long)t*(32*512) + region + tid*8) = ov;
    }
    if (w == 5 && t < TT-1) {                // wave5: MALL poll for t+1 -> doorbell
      if (!dead) {
        const unsigned tgt = (unsigned)(L*(TT-1) + t + 1);
        const unsigned* fp = fl + (lane & 31);
        unsigned tries = 0;
        for (;;) {
          unsigned v0, v1, v2, v3;
          asm volatile(
            "global_load_dword %0, %4, off sc0 sc1\n\t"
            "global_load_dword %1, %4, off sc0 sc1\n\t"
            "global_load_dword %2, %4, off sc0 sc1\n\t"
            "global_load_dword %3, %4, off sc0 sc1"
            : "=&v"(v0), "=&v"(v1), "=&v"(v2), "=&v"(v3)
            : "v"(fp) : "memory");
          asm volatile("s_waitcnt vmcnt(3)" ::: "memory");
          __builtin_amdgcn_sched_barrier(0);
          if (__all(v0 >= tgt)) break;
          asm volatile("s_waitcnt vmcnt(2)" ::: "memory");
          __builtin_amdgcn_sched_barrier(0);
          if (__all(v1 >= tgt)) break;
          asm volatile("s_waitcnt vmcnt(1)" ::: "memory");
          __builtin_amdgcn_sched_barrier(0);
          if (__all(v2 >= tgt)) break;
          asm volatile("s_waitcnt vmcnt(0)" ::: "memory");
          __builtin_amdgcn_sched_barrier(0);
          if (__all(v3 >= tgt)) break;
          if (++tries > (1u<<17)) { dead = 1; break; }   // visible fail, no wedge
        }
        asm volatile("s_waitcnt vmcnt(0)" ::: "memory"); // drain stragglers
      }
      if (lane == 0)                          // post doorbell even if valve tripped
        __hip_atomic_store(&ldsFlag, (unsigned)(t + 1), __ATOMIC_RELEASE,
                           __HIP_MEMORY_SCOPE_WORKGROUP);
    }
  }
}

// ---------------- decoder: relu(tanh(o3) @ Wd^T + bd) ----------------
__global__ __launch_bounds__(256, 2) void decoder_k(
    const _Float16* __restrict__ o3,
    const _Float16* __restrict__ wdbuf,
    const float* __restrict__ bdbuf,
    float* __restrict__ out)
{
  const int bx = blockIdx.x;          // 8 tiles * 25 chunks
  const int tile = bx & 7;
  const int chunk = bx >> 3;
  const int tid = threadIdx.x;
  const int w = tid >> 6, lane = tid & 63;
  __shared__ float ldsD[4][96][32];
  __shared__ float ldsO[32][73];      // 73: conflict-free write stride

  half8 Wf[3][8];
  {
    int kc = (lane >> 5) << 3;
    #pragma unroll
    for (int mt = 0; mt < 3; ++mt)
      #pragma unroll
      for (int i = 0; i < 8; ++i) {
        int row = mt*32 + (lane & 31);
        int k = (w*8 + i)*16 + kc;
        Wf[mt][i] = *(const half8*)(wdbuf + (long)row*512 + k);
      }
  }
  for (int tt = 0; tt < 8; ++tt) {
    int t = chunk*8 + tt;
    long ob = ((long)tile*200 + t)*(32*512);
    half8 Xf[8];
    #pragma unroll
    for (int i = 0; i < 8; ++i) {
      int s = w*8 + i;
      Xf[i] = *(const half8*)(o3 + ob + (long)s*512 + lane*8);
    }
    floatx16 C0, C1, C2;
    #pragma unroll
    for (int i = 0; i < 16; ++i) { C0[i] = 0.f; C1[i] = 0.f; C2[i] = 0.f; }
    #pragma unroll
    for (int i = 0; i < 8; ++i) {
      C0 = __builtin_amdgcn_mfma_f32_32x32x16_f16(Wf[0][i], Xf[i], C0, 0, 0, 0);
      C1 = __builtin_amdgcn_mfma_f32_32x32x16_f16(Wf[1][i], Xf[i], C1, 0, 0, 0);
      C2 = __builtin_amdgcn_mfma_f32_32x32x16_f16(Wf[2][i], Xf[i], C2, 0, 0, 0);
    }
    {
      int col = lane & 31;
      int rb = (lane >> 5) << 2;
      #pragma unroll
      for (int r = 0; r < 16; ++r) {
        int rowm = (r & 3) + 8*(r >> 2) + rb;
        ldsD[w][rowm][col]      = C0[r];
        ldsD[w][32 + rowm][col] = C1[r];
        ldsD[w][64 + rowm][col] = C2[r];
      }
    }
    __syncthreads();
    for (int ii = tid; ii < VV*32; ii += 256) {          // b-major: stride-1 LDS reads
      int bb = ii & 31, v = ii >> 5;
      float s = ldsD[0][v][bb] + ldsD[1][v][bb] + ldsD[2][v][bb] + ldsD[3][v][bb] + bdbuf[v];
      ldsO[bb][v] = s > 0.f ? s : 0.f;
    }
    __syncthreads();
    for (int ii = tid; ii < VV*32; ii += 256) {          // coalesced global writes
      int bb = ii / VV, v = ii - bb*VV;
      out[((long)(tile*32 + bb)*200 + t)*VV + v] = ldsO[bb][v];
    }
    __syncthreads();
  }
}

// ---------------- host ----------------
extern "C" void kernel_launch(void* const* d_in, const int* in_sizes, int n_in,
                              void* d_out, int out_size, void* d_ws, size_t ws_size,
                              hipStream_t stream) {
  (void)in_sizes; (void)n_in;
  const float* x    = (const float*)d_in[0];
  const float* wih1 = (const float*)d_in[1];
  const float* whh1 = (const float*)d_in[2];
  const float* bih1 = (const float*)d_in[3];
  const float* bhh1 = (const float*)d_in[4];
  const float* wih2 = (const float*)d_in[5];
  const float* whh2 = (const float*)d_in[6];
  const float* bih2 = (const float*)d_in[7];
  const float* bhh2 = (const float*)d_in[8];
  const float* wih3 = (const float*)d_in[9];
  const float* whh3 = (const float*)d_in[10];
  const float* bih3 = (const float*)d_in[11];
  const float* bhh3 = (const float*)d_in[12];
  const float* wd   = (const float*)d_in[13];
  const float* bd   = (const float*)d_in[14];
  char* ws = (char*)d_ws;

  if (ws_size < WS_NEED) {   // clean, visible failure rather than corruption
    hipMemsetAsync(d_out, 0, (size_t)out_size*sizeof(float), stream);
    return;
  }

  _Float16* wbuf   = (_Float16*)(ws + OFF_W);
  float*    gi1p   = (float*)(ws + OFF_GI1);
  float*    biasp  = (float*)(ws + OFF_BIAS);
  _Float16* wdbufp = (_Float16*)(ws + OFF_WD);
  float*    bdbufp = (float*)(ws + OFF_BD);
  _Float16* hfragp = (_Float16*)(ws + OFF_HFRAG);
  float*    hfinp  = (float*)(ws + OFF_HFIN);
  unsigned* flagsp = (unsigned*)(ws + OFF_BAR);
  _Float16* ob0    = (_Float16*)(ws + OFF_OFRAG);
  _Float16* ob1    = ob0 + SZ_OBUF/2;

  // zero flags each launch (memory-side MALL => visible to sc0sc1 readers)
  hipMemsetAsync(ws + OFF_BAR, 0, 4096, stream);

  prep_weights<<<4096, 256, 0, stream>>>(wih1, whh1, wih2, whh2, wih3, whh3, wbuf);
  prep_misc<<<1024, 256, 0, stream>>>(x, wih1, bih1, bhh1, bih2, bhh2, bih3, bhh3,
                                      wd, bd, gi1p, biasp, wdbufp, bdbufp);

  gru_layer_k<0><<<256, 512, 0, stream>>>(wbuf, ob1, ob0, hfragp, hfinp, gi1p, biasp, flagsp);
  gru_layer_k<1><<<256, 512, 0, stream>>>(wbuf, ob0, ob1, hfragp, hfinp, gi1p, biasp, flagsp);
  gru_layer_k<2><<<256, 512, 0, stream>>>(wbuf, ob1, ob0, hfragp, hfinp, gi1p, biasp, flagsp);

  decoder_k<<<200, 256, 0, stream>>>(ob0, wdbufp, bdbufp, (float*)d_out);
}